// Round 5
// baseline (250.075 us; speedup 1.0000x reference)
//
#include <hip/hip_runtime.h>

// LPC synthesis (AR(15), frame-hopped coefs) + de-emphasis IIR.
// Truncated-history recomputation, one output frame per lane, 3-frame
// (240-sample) warm-up. De-emph truncation 0.97^240*|z|max ~ 1.5e-2 vs
// threshold 4.56e-2 (measured absmax 1.56e-2). Frames 0..2 exact.
//
// R5: (a) LDS staging replaces R4's shuffle choreography — each thread
// stages its frame (20xb128, stride 84 floats = 16B-aligned) + negated taps
// (stride 17, conflict-free) ONCE; invalid frames zeroed at staging so the
// t-loop needs no masking. (b) 3-way accumulator split (5+5+5 taps) breaks
// the serial 15-fma chain: cross-sample critical path = 1 fma + 1 add
// (8 cyc) vs 36 cyc issue -> issue-bound even at 1.5 waves/SIMD.
// R3 lesson: no large per-lane arrays (scratch spill).

namespace {
constexpr int kFS = 80;        // frame shift
constexpr int kF = 3000;       // frames per batch
constexpr int kL = kFS * kF;   // 240000
constexpr int kOrder = 16;
constexpr int kB = 64;
constexpr float kEmph = 0.97f;
constexpr int kThreads = 128;          // 2 waves/block
constexpr int kEmit = kThreads - 3;    // 125 emit frames per block
constexpr int kSE = 84;  // excit LDS stride (floats): 84*4=336 16B-aligned
constexpr int kSC = 17;  // tap LDS stride: gcd(17,32)=1 -> conflict-free

typedef float vfloat4 __attribute__((ext_vector_type(4)));
}  // namespace

__global__ __launch_bounds__(kThreads) void lpc_synth_kernel(
    const float* __restrict__ excit, const float* __restrict__ coef,
    float* __restrict__ out) {
  __shared__ float s_e[kThreads * kSE];  // 43008 B
  __shared__ float s_c[kThreads * kSC];  //  8704 B

  const int tid = threadIdx.x;
  const int b = blockIdx.y;
  const int fbase = blockIdx.x * kEmit;
  const int Lf = fbase - 3 + tid;  // frame this thread stages == emits
  const bool lvalid = (Lf >= 0) && (Lf < kF);
  const int Lc = min(max(Lf, 0), kF - 1);

  // ---- Stage excitation frame (one burst of 20 x 16B).
  const vfloat4* __restrict__ ep =
      (const vfloat4*)(excit + (size_t)b * kL + (size_t)Lc * kFS);
  vfloat4* se = (vfloat4*)(s_e + tid * kSE);
#pragma unroll
  for (int j = 0; j < 20; ++j) {
    vfloat4 v = ep[j];
    if (!lvalid) v = 0.f;
    se[j] = v;
  }

  // ---- Stage negated taps (zeroed if invalid -> warm-up==zero-state).
  const vfloat4* __restrict__ cp =
      (const vfloat4*)(coef + ((size_t)b * kF + Lc) * kOrder);
  vfloat4 c0 = cp[0], c1 = cp[1], c2 = cp[2], c3 = cp[3];
  if (!lvalid) { c0 = 0.f; c1 = 0.f; c2 = 0.f; c3 = 0.f; }
  {
    float* sc = s_c + tid * kSC;
    sc[0] = -c0.y;  sc[1] = -c0.z;  sc[2] = -c0.w;  sc[3] = -c1.x;
    sc[4] = -c1.y;  sc[5] = -c1.z;  sc[6] = -c1.w;  sc[7] = -c2.x;
    sc[8] = -c2.y;  sc[9] = -c2.z;  sc[10] = -c2.w; sc[11] = -c3.x;
    sc[12] = -c3.y; sc[13] = -c3.z; sc[14] = -c3.w;
  }
  __syncthreads();  // LDS is read-only below; no further barriers.

  // Ring buffer of last 16 y-samples (slot = n mod 16; 80%16==0 keeps frame
  // starts aligned). Compile-time indexed -> VGPRs.
  float x[16];
#pragma unroll
  for (int i = 0; i < 16; ++i) x[i] = 0.f;
  float z = 0.f;

  const bool emit = (tid >= 3);  // by grid construction Lf<kF always
  vfloat4* __restrict__ op =
      (vfloat4*)(out + (size_t)b * kL + (size_t)Lc * kFS);

#pragma unroll 1
  for (int t = 0; t < 4; ++t) {  // 3 warm-up frames + 1 emit frame
    const int slot = max(tid - 3 + t, 0);  // lanes 0..2 compute junk, no emit

    const float* scs = s_c + slot * kSC;
    float na[15];
#pragma unroll
    for (int k = 0; k < 15; ++k) na[k] = scs[k];

    const vfloat4* ses = (const vfloat4*)(s_e + slot * kSE);

#pragma unroll
    for (int j = 0; j < 20; ++j) {
      const vfloat4 ev = ses[j];
      float st[4];
#pragma unroll
      for (int q = 0; q < 4; ++q) {
        const int s = 4 * j + q;
        // 3 partial accumulators: a0 = e + taps 11..15 (oldest),
        // a1 = taps 6..10, a2 = taps 1..5 with the x[s-1] term LAST.
        float a0 = ev[q];
        a0 = fmaf(na[14], x[(s - 15) & 15], a0);
        a0 = fmaf(na[13], x[(s - 14) & 15], a0);
        a0 = fmaf(na[12], x[(s - 13) & 15], a0);
        a0 = fmaf(na[11], x[(s - 12) & 15], a0);
        a0 = fmaf(na[10], x[(s - 11) & 15], a0);
        float a1 = na[9] * x[(s - 10) & 15];
        a1 = fmaf(na[8], x[(s - 9) & 15], a1);
        a1 = fmaf(na[7], x[(s - 8) & 15], a1);
        a1 = fmaf(na[6], x[(s - 7) & 15], a1);
        a1 = fmaf(na[5], x[(s - 6) & 15], a1);
        float a2 = na[4] * x[(s - 5) & 15];
        a2 = fmaf(na[3], x[(s - 4) & 15], a2);
        a2 = fmaf(na[2], x[(s - 3) & 15], a2);
        a2 = fmaf(na[1], x[(s - 2) & 15], a2);
        const float a01 = a0 + a1;                   // off critical path
        a2 = fmaf(na[0], x[(s - 1) & 15], a2);       // critical: 1 fma
        const float acc = a01 + a2;                  // + 1 add = 8 cyc/sample
        x[s & 15] = acc;
        z = fmaf(kEmph, z, acc);  // de-emphasis IIR
        st[q] = z;
      }
      if (t == 3 && emit) {
        vfloat4 v;
        v.x = st[0]; v.y = st[1]; v.z = st[2]; v.w = st[3];
        // Write-once stream: keep out of L2/L3 so excitation stays cached.
        __builtin_nontemporal_store(v, op + j);
      }
    }
  }
}

extern "C" void kernel_launch(void* const* d_in, const int* in_sizes, int n_in,
                              void* d_out, int out_size, void* d_ws,
                              size_t ws_size, hipStream_t stream) {
  const float* excit = (const float*)d_in[0];  // (B, L, 1) fp32
  const float* coef = (const float*)d_in[1];   // (B, F, 16) fp32
  float* out = (float*)d_out;                  // (B, L, 1) fp32

  dim3 grid((kF + kEmit - 1) / kEmit, kB);  // 24 x 64 blocks of 128
  lpc_synth_kernel<<<grid, kThreads, 0, stream>>>(excit, coef, out);
}

// Round 6
// 146.725 us; speedup vs baseline: 1.7044x; 1.7044x over previous
//
#include <hip/hip_runtime.h>

// LPC synthesis (AR(15), frame-hopped coefs) + de-emphasis IIR.
// Truncated-history recomputation, one output frame per lane, 3-frame
// (240-sample) warm-up. De-emph truncation 0.97^240*|z|max ~ 1.5e-2 vs
// threshold 4.56e-2 (measured absmax 1.56e-2). Frames 0..2 exact.
//
// R5: LDS staging (each thread stages its frame + negated taps once;
// invalid frames zeroed at staging) + 3-way accumulator split so the
// cross-sample critical path is 1 fma + 1 add (8 cyc) vs 36 cyc issue.
// R6: PLAIN output stores. __builtin_nontemporal_store at 320B lane stride
// defeated L2 write-coalescing: 61 MB of output became ~200 MB of
// partial-line HBM writes (R3 AND R5 regressions — WRITE_SIZE 180/200 MB).
// Plain stores let L2 assemble full lines (R4 measured 67 MB). Nontemporal
// is only safe when each store instruction is full-line coalesced.
// R3 lesson: no large per-lane arrays (scratch spill).

namespace {
constexpr int kFS = 80;        // frame shift
constexpr int kF = 3000;       // frames per batch
constexpr int kL = kFS * kF;   // 240000
constexpr int kOrder = 16;
constexpr int kB = 64;
constexpr float kEmph = 0.97f;
constexpr int kThreads = 128;          // 2 waves/block
constexpr int kEmit = kThreads - 3;    // 125 emit frames per block
constexpr int kSE = 84;  // excit LDS stride (floats): 84*4=336, 16B-aligned
constexpr int kSC = 17;  // tap LDS stride: gcd(17,32)=1 -> conflict-free

typedef float vfloat4 __attribute__((ext_vector_type(4)));
}  // namespace

__global__ __launch_bounds__(kThreads) void lpc_synth_kernel(
    const float* __restrict__ excit, const float* __restrict__ coef,
    float* __restrict__ out) {
  __shared__ float s_e[kThreads * kSE];  // 43008 B
  __shared__ float s_c[kThreads * kSC];  //  8704 B

  const int tid = threadIdx.x;
  const int b = blockIdx.y;
  const int fbase = blockIdx.x * kEmit;
  const int Lf = fbase - 3 + tid;  // frame this thread stages == emits
  const bool lvalid = (Lf >= 0) && (Lf < kF);
  const int Lc = min(max(Lf, 0), kF - 1);

  // ---- Stage excitation frame (one burst of 20 x 16B).
  const vfloat4* __restrict__ ep =
      (const vfloat4*)(excit + (size_t)b * kL + (size_t)Lc * kFS);
  vfloat4* se = (vfloat4*)(s_e + tid * kSE);
#pragma unroll
  for (int j = 0; j < 20; ++j) {
    vfloat4 v = ep[j];
    if (!lvalid) v = 0.f;
    se[j] = v;
  }

  // ---- Stage negated taps (zeroed if invalid -> warm-up==zero-state).
  const vfloat4* __restrict__ cp =
      (const vfloat4*)(coef + ((size_t)b * kF + Lc) * kOrder);
  vfloat4 c0 = cp[0], c1 = cp[1], c2 = cp[2], c3 = cp[3];
  if (!lvalid) { c0 = 0.f; c1 = 0.f; c2 = 0.f; c3 = 0.f; }
  {
    float* sc = s_c + tid * kSC;
    sc[0] = -c0.y;  sc[1] = -c0.z;  sc[2] = -c0.w;  sc[3] = -c1.x;
    sc[4] = -c1.y;  sc[5] = -c1.z;  sc[6] = -c1.w;  sc[7] = -c2.x;
    sc[8] = -c2.y;  sc[9] = -c2.z;  sc[10] = -c2.w; sc[11] = -c3.x;
    sc[12] = -c3.y; sc[13] = -c3.z; sc[14] = -c3.w;
  }
  __syncthreads();  // LDS is read-only below; no further barriers.

  // Ring buffer of last 16 y-samples (slot = n mod 16; 80%16==0 keeps frame
  // starts aligned). Compile-time indexed -> VGPRs.
  float x[16];
#pragma unroll
  for (int i = 0; i < 16; ++i) x[i] = 0.f;
  float z = 0.f;

  const bool emit = (tid >= 3);  // by grid construction Lf<kF always
  vfloat4* __restrict__ op =
      (vfloat4*)(out + (size_t)b * kL + (size_t)Lc * kFS);

#pragma unroll 1
  for (int t = 0; t < 4; ++t) {  // 3 warm-up frames + 1 emit frame
    const int slot = max(tid - 3 + t, 0);  // lanes 0..2 compute junk, no emit

    const float* scs = s_c + slot * kSC;
    float na[15];
#pragma unroll
    for (int k = 0; k < 15; ++k) na[k] = scs[k];

    const vfloat4* ses = (const vfloat4*)(s_e + slot * kSE);

#pragma unroll
    for (int j = 0; j < 20; ++j) {
      const vfloat4 ev = ses[j];
      float st[4];
#pragma unroll
      for (int q = 0; q < 4; ++q) {
        const int s = 4 * j + q;
        // 3 partial accumulators: a0 = e + taps 11..15 (oldest),
        // a1 = taps 6..10, a2 = taps 1..5 with the x[s-1] term LAST.
        float a0 = ev[q];
        a0 = fmaf(na[14], x[(s - 15) & 15], a0);
        a0 = fmaf(na[13], x[(s - 14) & 15], a0);
        a0 = fmaf(na[12], x[(s - 13) & 15], a0);
        a0 = fmaf(na[11], x[(s - 12) & 15], a0);
        a0 = fmaf(na[10], x[(s - 11) & 15], a0);
        float a1 = na[9] * x[(s - 10) & 15];
        a1 = fmaf(na[8], x[(s - 9) & 15], a1);
        a1 = fmaf(na[7], x[(s - 8) & 15], a1);
        a1 = fmaf(na[6], x[(s - 7) & 15], a1);
        a1 = fmaf(na[5], x[(s - 6) & 15], a1);
        float a2 = na[4] * x[(s - 5) & 15];
        a2 = fmaf(na[3], x[(s - 4) & 15], a2);
        a2 = fmaf(na[2], x[(s - 3) & 15], a2);
        a2 = fmaf(na[1], x[(s - 2) & 15], a2);
        const float a01 = a0 + a1;                   // off critical path
        a2 = fmaf(na[0], x[(s - 1) & 15], a2);       // critical: 1 fma
        const float acc = a01 + a2;                  // + 1 add = 8 cyc/sample
        x[s & 15] = acc;
        z = fmaf(kEmph, z, acc);  // de-emphasis IIR
        st[q] = z;
      }
      if (t == 3 && emit) {
        vfloat4 v;
        v.x = st[0]; v.y = st[1]; v.z = st[2]; v.w = st[3];
        op[j] = v;  // plain store: L2 assembles full lines (see R6 note)
      }
    }
  }
}

extern "C" void kernel_launch(void* const* d_in, const int* in_sizes, int n_in,
                              void* d_out, int out_size, void* d_ws,
                              size_t ws_size, hipStream_t stream) {
  const float* excit = (const float*)d_in[0];  // (B, L, 1) fp32
  const float* coef = (const float*)d_in[1];   // (B, F, 16) fp32
  float* out = (float*)d_out;                  // (B, L, 1) fp32

  dim3 grid((kF + kEmit - 1) / kEmit, kB);  // 24 x 64 blocks of 128
  lpc_synth_kernel<<<grid, kThreads, 0, stream>>>(excit, coef, out);
}